// Round 1
// baseline (2085.420 us; speedup 1.0000x reference)
//
#include <hip/hip_runtime.h>

typedef unsigned short u16;
typedef __attribute__((ext_vector_type(8))) short bf16x8;
typedef __attribute__((ext_vector_type(4))) float f32x4;

#define DD 2048
#define VV 10000
#define BB 32
#define TT 20

__device__ __forceinline__ u16 f2bf(float f) {
    unsigned u = __float_as_uint(f);
    u += 0x7fffu + ((u >> 16) & 1u);
    return (u16)(u >> 16);
}
__device__ __forceinline__ float bf2f(u16 h) {
    return __uint_as_float(((unsigned)h) << 16);
}

// ---------------------------------------------------------------------------
// One-time: cast the three per-step weight matrices to bf16.
// Wcat_a[8192][4096] = [Wih_a[:,0:2048] | Whh_a]      (x = [h_l ; h_a])
// Wcat_l[8192][4096] = [Wih_l[:,0:2048] | Whh_l]      (x = [h_a ; h_l])
// Wfc_b [10000][2048]
// ---------------------------------------------------------------------------
__global__ __launch_bounds__(256) void cast_weights(
    const float* __restrict__ Wih_a, const float* __restrict__ Whh_a,
    const float* __restrict__ Wih_l, const float* __restrict__ Whh_l,
    const float* __restrict__ Wfc,
    u16* __restrict__ Wcat_a, u16* __restrict__ Wcat_l, u16* __restrict__ Wfc_b)
{
    const long long S1 = 8192LL * 4096;
    const long long S3 = 20480000LL; // 10000*2048
    long long g = (long long)blockIdx.x * 256 + threadIdx.x;
    long long e = g * 4;
    const float* src;
    u16* dst;
    if (e < S1) {
        int n = (int)(e >> 12), k = (int)(e & 4095);
        src = (k < 2048) ? (Wih_a + (size_t)n * 6144 + k)
                         : (Whh_a + (size_t)n * 2048 + (k - 2048));
        dst = Wcat_a + e;
    } else if (e < 2 * S1) {
        long long e2 = e - S1;
        int n = (int)(e2 >> 12), k = (int)(e2 & 4095);
        src = (k < 2048) ? (Wih_l + (size_t)n * 4096 + k)
                         : (Whh_l + (size_t)n * 2048 + (k - 2048));
        dst = Wcat_l + e2;
    } else {
        long long e3 = e - 2 * S1;
        if (e3 >= S3) return;
        src = Wfc + e3;
        dst = Wfc_b + e3;
    }
    float4 v = *(const float4*)src;
    ushort4 o;
    o.x = f2bf(v.x); o.y = f2bf(v.y); o.z = f2bf(v.z); o.w = f2bf(v.w);
    *(ushort4*)dst = o;
}

// ---------------------------------------------------------------------------
// One-time: v_bar (mean over X), v_hat (sum over X -- attention weights are
// all-ones because softmax is over a singleton axis), zero the LSTM states.
// ---------------------------------------------------------------------------
__global__ __launch_bounds__(256) void prep(
    const float* __restrict__ features,
    u16* __restrict__ vbar, u16* __restrict__ vhat,
    float* __restrict__ c_a, float* __restrict__ c_l,
    u16* __restrict__ Ha0, u16* __restrict__ Hl0)
{
    int i = blockIdx.x * 256 + threadIdx.x;           // 32*2048
    int b = i >> 11, d = i & 2047;
    const float* f = features + (size_t)b * 36 * 2048 + d;
    float s = 0.f;
#pragma unroll
    for (int x = 0; x < 36; ++x) s += f[(size_t)x * 2048];
    vhat[i] = f2bf(s);
    vbar[i] = f2bf(s * (1.f / 36.f));
    c_a[i] = 0.f; c_l[i] = 0.f;
    Ha0[i] = 0;  Hl0[i] = 0;
}

// embedding gather -> bf16, rows m = t*32 + b
__global__ __launch_bounds__(256) void embed_k(
    const float* __restrict__ emb, const int* __restrict__ caption,
    u16* __restrict__ embs)
{
    int i = blockIdx.x * 256 + threadIdx.x;           // 640*2048
    int m = i >> 11, d = i & 2047;
    int t = m >> 5, b = m & 31;
    int tok = caption[b * TT + t];
    embs[i] = f2bf(emb[(size_t)tok * 2048 + d]);
}

// ---------------------------------------------------------------------------
// Precompute GEMM: out[m][n] = sum_k A[m][k]*W[n][kofs+k] (+bias0[n]+bias1[n])
// (+addend[m&31][n]).  A bf16 [M,2048]; W fp32 (cast inline).  N = 8192.
// block = 256 thr (4 waves x 16 n-cols); m-chunk = MT*16 rows per block.y
// Explicit 1-deep register prefetch pipeline to keep loads in flight.
// ---------------------------------------------------------------------------
template <int MT>
__global__ __launch_bounds__(256) void pre_gemm(
    const u16* __restrict__ A, const float* __restrict__ W,
    int ldw, int kofs,
    const float* __restrict__ bias0, const float* __restrict__ bias1,
    const float* __restrict__ addend, float* __restrict__ out)
{
    const int lane = threadIdx.x & 63;
    const int wv = threadIdx.x >> 6;
    const int lr = lane & 15, lq = lane >> 4;
    const int n0 = blockIdx.x * 64 + wv * 16;
    const int m0 = blockIdx.y * (MT * 16);

    f32x4 acc[MT];
#pragma unroll
    for (int i = 0; i < MT; ++i) acc[i] = (f32x4){0.f, 0.f, 0.f, 0.f};

    const float* wrow = W + (size_t)(n0 + lr) * ldw + kofs + lq * 8;
    const u16* arow = A + (size_t)(m0 + lr) * 2048 + lq * 8;

    float4 wlon = *(const float4*)(wrow);
    float4 whin = *(const float4*)(wrow + 4);
    bf16x8 afn[MT];
#pragma unroll
    for (int mt = 0; mt < MT; ++mt)
        afn[mt] = *(const bf16x8*)(arow + (size_t)mt * 16 * 2048);

    for (int k = 0; k < 2048; k += 32) {
        float4 wlo = wlon, whi = whin;
        bf16x8 afc[MT];
#pragma unroll
        for (int mt = 0; mt < MT; ++mt) afc[mt] = afn[mt];
        if (k + 32 < 2048) {
            wlon = *(const float4*)(wrow + k + 32);
            whin = *(const float4*)(wrow + k + 36);
#pragma unroll
            for (int mt = 0; mt < MT; ++mt)
                afn[mt] = *(const bf16x8*)(arow + (size_t)mt * 16 * 2048 + k + 32);
        }
        bf16x8 bf;
        bf[0] = (short)f2bf(wlo.x); bf[1] = (short)f2bf(wlo.y);
        bf[2] = (short)f2bf(wlo.z); bf[3] = (short)f2bf(wlo.w);
        bf[4] = (short)f2bf(whi.x); bf[5] = (short)f2bf(whi.y);
        bf[6] = (short)f2bf(whi.z); bf[7] = (short)f2bf(whi.w);
#pragma unroll
        for (int mt = 0; mt < MT; ++mt)
            acc[mt] = __builtin_amdgcn_mfma_f32_16x16x32_bf16(afc[mt], bf, acc[mt], 0, 0, 0);
    }
    const int n = n0 + lr;
    float badd = 0.f;
    if (bias0) badd += bias0[n];
    if (bias1) badd += bias1[n];
#pragma unroll
    for (int mt = 0; mt < MT; ++mt) {
#pragma unroll
        for (int r = 0; r < 4; ++r) {
            int m = m0 + mt * 16 + lq * 4 + r;
            float v = acc[mt][r] + badd;
            if (addend) v += addend[(size_t)(m & 31) * 8192 + n];
            out[(size_t)m * 8192 + n] = v;
        }
    }
}

// ---------------------------------------------------------------------------
// Sequential step kernel v2: full-GPU grid + deep load pipelining.
// grid 512 blocks x 256 threads (4 waves).  Each block owns 4 d-cols x 4
// gates = 16 rows of W; wave w handles K-slice [w*1024, w*1024+1024).
// A = [A0 | A1] along K (each [32,2048] bf16).  W = [8192,4096] bf16.
// K-loop fully unrolled (32 iters, all loads base+imm) so the scheduler can
// hoist loads far ahead of the MFMAs -> latency-tolerant weight streaming.
// ---------------------------------------------------------------------------
__global__ __launch_bounds__(256) void step_kernel(
    const u16* __restrict__ A0, const u16* __restrict__ A1,
    const u16* __restrict__ W, const float* __restrict__ zconst,
    float* __restrict__ c, u16* __restrict__ hout)
{
    __shared__ float zred[4][32][16];   // 8 KB
    const int lane = threadIdx.x & 63;
    const int w = threadIdx.x >> 6;          // 0..3 : K-slice
    const int lr = lane & 15, lq = lane >> 4;
    const int d0 = blockIdx.x * 4;           // 512 blocks cover 2048 d-cols

    const int g = lr >> 2, dd = lr & 3;      // 16 W-rows: 4 gates x 4 d
    const int nrow = g * 2048 + d0 + dd;

    const u16* Aptr = (w < 2) ? A0 : A1;     // K 0..2047 -> A0, 2048..4095 -> A1
    const int kA = (w & 1) * 1024 + lq * 8;
    const int kW = w * 1024 + lq * 8;

    f32x4 acc0 = (f32x4){0.f, 0.f, 0.f, 0.f};
    f32x4 acc1 = (f32x4){0.f, 0.f, 0.f, 0.f};

    const u16* a_row0 = Aptr + (size_t)lr * 2048 + kA;
    const u16* a_row1 = Aptr + (size_t)(16 + lr) * 2048 + kA;
    const u16* b_row  = W + (size_t)nrow * 4096 + kW;

    bf16x8 a0n = *(const bf16x8*)(a_row0);
    bf16x8 a1n = *(const bf16x8*)(a_row1);
    bf16x8 bn  = *(const bf16x8*)(b_row);
#pragma unroll
    for (int kk = 0; kk < 1024; kk += 32) {
        bf16x8 a0 = a0n, a1 = a1n, b = bn;
        if (kk + 32 < 1024) {
            a0n = *(const bf16x8*)(a_row0 + kk + 32);
            a1n = *(const bf16x8*)(a_row1 + kk + 32);
            bn  = *(const bf16x8*)(b_row  + kk + 32);
        }
        acc0 = __builtin_amdgcn_mfma_f32_16x16x32_bf16(a0, b, acc0, 0, 0, 0);
        acc1 = __builtin_amdgcn_mfma_f32_16x16x32_bf16(a1, b, acc1, 0, 0, 0);
    }

    // K-partials across the 4 waves via LDS
#pragma unroll
    for (int r = 0; r < 4; ++r) {
        zred[w][lq * 4 + r][lr]      = acc0[r];
        zred[w][16 + lq * 4 + r][lr] = acc1[r];
    }
    __syncthreads();

    // gates: 128 threads <-> (b, j) with j in 0..3 (d = d0+j)
    if (threadIdx.x < 128) {
        const int b = threadIdx.x >> 2;
        const int j = threadIdx.x & 3;
        const int d = d0 + j;
        float z[4];
#pragma unroll
        for (int gg = 0; gg < 4; ++gg) {
            float s = zconst[(size_t)b * 8192 + gg * 2048 + d];
#pragma unroll
            for (int wv = 0; wv < 4; ++wv) s += zred[wv][b][gg * 4 + j];
            z[gg] = s;
        }
        float ig = 1.f / (1.f + __expf(-z[0]));
        float fg = 1.f / (1.f + __expf(-z[1]));
        float gv = tanhf(z[2]);
        float og = 1.f / (1.f + __expf(-z[3]));
        float cn = fg * c[(size_t)b * 2048 + d] + ig * gv;
        c[(size_t)b * 2048 + d] = cn;
        hout[(size_t)b * 2048 + d] = f2bf(og * tanhf(cn));
    }
}

// ---------------------------------------------------------------------------
// Logits GEMM: out[b][t][n] = sum_k Hl[t+1][b][k]*Wfc_b[n][k] + bfc[n]
// A rows m = t*32+b.  N = 10000 (625 16-tiles).
// Explicit 1-deep register prefetch (11 loads in flight per wave).
// ---------------------------------------------------------------------------
template <int MT>
__global__ __launch_bounds__(256) void logits_gemm(
    const u16* __restrict__ A, const u16* __restrict__ Wb,
    const float* __restrict__ bias, float* __restrict__ out)
{
    const int lane = threadIdx.x & 63;
    const int wv = threadIdx.x >> 6;
    const int lr = lane & 15, lq = lane >> 4;
    const int n0 = blockIdx.x * 64 + wv * 16;
    if (n0 >= VV) return;
    const int m0 = blockIdx.y * (MT * 16);

    f32x4 acc[MT];
#pragma unroll
    for (int i = 0; i < MT; ++i) acc[i] = (f32x4){0.f, 0.f, 0.f, 0.f};

    const u16* wrow = Wb + (size_t)(n0 + lr) * 2048 + lq * 8;
    const u16* arow = A + (size_t)(m0 + lr) * 2048 + lq * 8;

    bf16x8 bfn = *(const bf16x8*)(wrow);
    bf16x8 afn[MT];
#pragma unroll
    for (int mt = 0; mt < MT; ++mt)
        afn[mt] = *(const bf16x8*)(arow + (size_t)mt * 16 * 2048);

    for (int k = 0; k < 2048; k += 32) {
        bf16x8 bfc = bfn;
        bf16x8 afc[MT];
#pragma unroll
        for (int mt = 0; mt < MT; ++mt) afc[mt] = afn[mt];
        if (k + 32 < 2048) {
            bfn = *(const bf16x8*)(wrow + k + 32);
#pragma unroll
            for (int mt = 0; mt < MT; ++mt)
                afn[mt] = *(const bf16x8*)(arow + (size_t)mt * 16 * 2048 + k + 32);
        }
#pragma unroll
        for (int mt = 0; mt < MT; ++mt)
            acc[mt] = __builtin_amdgcn_mfma_f32_16x16x32_bf16(afc[mt], bfc, acc[mt], 0, 0, 0);
    }
    const int n = n0 + lr;
    const float bv = bias[n];
#pragma unroll
    for (int mt = 0; mt < MT; ++mt) {
#pragma unroll
        for (int r = 0; r < 4; ++r) {
            int m = m0 + mt * 16 + lq * 4 + r;
            int t = m >> 5, b = m & 31;
            out[(size_t)b * (TT * VV) + (size_t)t * VV + n] = acc[mt][r] + bv;
        }
    }
}

// in-place log-softmax over rows of 10000
__global__ __launch_bounds__(256) void logsoftmax(float* __restrict__ out)
{
    float* p = out + (size_t)blockIdx.x * VV;
    const int tid = threadIdx.x, lane = tid & 63, wv = tid >> 6;
    __shared__ float red[4], red2[4];
    float mx = -1e30f;
    for (int i = tid; i < VV; i += 256) mx = fmaxf(mx, p[i]);
    for (int o = 32; o > 0; o >>= 1) mx = fmaxf(mx, __shfl_down(mx, o, 64));
    if (lane == 0) red[wv] = mx;
    __syncthreads();
    mx = fmaxf(fmaxf(red[0], red[1]), fmaxf(red[2], red[3]));
    float sum = 0.f;
    for (int i = tid; i < VV; i += 256) sum += __expf(p[i] - mx);
    for (int o = 32; o > 0; o >>= 1) sum += __shfl_down(sum, o, 64);
    if (lane == 0) red2[wv] = sum;
    __syncthreads();
    sum = red2[0] + red2[1] + red2[2] + red2[3];
    const float lse = mx + __logf(sum);
    for (int i = tid; i < VV; i += 256) p[i] = p[i] - lse;
}

// ---------------------------------------------------------------------------
extern "C" void kernel_launch(void* const* d_in, const int* in_sizes, int n_in,
                              void* d_out, int out_size, void* d_ws, size_t ws_size,
                              hipStream_t stream)
{
    const float* features = (const float*)d_in[0];
    const int*   caption  = (const int*)d_in[1];
    const float* emb      = (const float*)d_in[2];
    const float* Wih_a    = (const float*)d_in[3];
    const float* Whh_a    = (const float*)d_in[4];
    const float* bih_a    = (const float*)d_in[5];
    const float* bhh_a    = (const float*)d_in[6];
    const float* Wih_l    = (const float*)d_in[7];
    const float* Whh_l    = (const float*)d_in[8];
    const float* bih_l    = (const float*)d_in[9];
    const float* bhh_l    = (const float*)d_in[10];
    // d_in[11..16] = Wv,bv,Wh,bh,Wa,ba : DEAD (softmax over singleton axis)
    const float* Wfc      = (const float*)d_in[17];
    const float* bfc      = (const float*)d_in[18];
    float* out = (float*)d_out;

    char* ws = (char*)d_ws;
    size_t off = 0;
    auto alloc = [&](size_t bytes) { void* p = ws + off; off += (bytes + 255) & ~(size_t)255; return p; };
    u16* Wcat_a  = (u16*)alloc(8192ull * 4096 * 2);       // 67.1 MB
    u16* Wcat_l  = (u16*)alloc(8192ull * 4096 * 2);       // 67.1 MB
    u16* Wfc_b   = (u16*)alloc(10000ull * 2048 * 2);      // 41.0 MB
    float* z_const = (float*)alloc(20ull * 32 * 8192 * 4);// 21.0 MB
    float* const_a = (float*)alloc(32ull * 8192 * 4);
    float* const_l = (float*)alloc(32ull * 8192 * 4);
    u16* embs    = (u16*)alloc(640ull * 2048 * 2);
    u16* vbar    = (u16*)alloc(32ull * 2048 * 2);
    u16* vhat    = (u16*)alloc(32ull * 2048 * 2);
    u16* Ha      = (u16*)alloc(2ull * 32 * 2048 * 2);
    u16* Hl      = (u16*)alloc(21ull * 32 * 2048 * 2);
    float* c_a   = (float*)alloc(32ull * 2048 * 4);
    float* c_l   = (float*)alloc(32ull * 2048 * 4);
    (void)ws_size; (void)in_sizes; (void)n_in; (void)out_size;

    // one-time precompute
    cast_weights<<<dim3(85536), dim3(256), 0, stream>>>(
        Wih_a, Whh_a, Wih_l, Whh_l, Wfc, Wcat_a, Wcat_l, Wfc_b);
    prep<<<dim3(256), dim3(256), 0, stream>>>(features, vbar, vhat, c_a, c_l, Ha, Hl);
    embed_k<<<dim3(5120), dim3(256), 0, stream>>>(emb, caption, embs);
    // const_a[b][n] = vbar @ Wih_a[:,2048:4096]^T + bih_a + bhh_a
    pre_gemm<2><<<dim3(128, 1), dim3(256), 0, stream>>>(
        vbar, Wih_a, 6144, 2048, bih_a, bhh_a, nullptr, const_a);
    // const_l[b][n] = vhat @ Wih_l[:,2048:4096]^T + bih_l + bhh_l
    pre_gemm<2><<<dim3(128, 1), dim3(256), 0, stream>>>(
        vhat, Wih_l, 4096, 2048, bih_l, bhh_l, nullptr, const_l);
    // z_const[t*32+b][n] = embs @ Wih_a[:,4096:6144]^T + const_a[b]
    pre_gemm<10><<<dim3(128, 4), dim3(256), 0, stream>>>(
        embs, Wih_a, 6144, 4096, nullptr, nullptr, const_a, z_const);

    // sequential 20-step dual-LSTM loop (2 fused GEMM+gate kernels per step)
    for (int t = 0; t < 20; ++t) {
        u16* hl_prev = Hl + (size_t)t * 65536;
        u16* ha_prev = Ha + (size_t)(t & 1) * 65536;
        u16* ha_new  = Ha + (size_t)((t + 1) & 1) * 65536;
        u16* hl_new  = Hl + (size_t)(t + 1) * 65536;
        // attention LSTM: x=[h_l ; h_a] vs [Wih_a[:,0:2048] | Whh_a]
        step_kernel<<<dim3(512), dim3(256), 0, stream>>>(
            hl_prev, ha_prev, Wcat_a, z_const + (size_t)t * 262144, c_a, ha_new);
        // language LSTM: x=[h_a ; h_l] vs [Wih_l[:,0:2048] | Whh_l]
        step_kernel<<<dim3(512), dim3(256), 0, stream>>>(
            ha_new, hl_prev, Wcat_l, const_l, c_l, hl_new);
    }

    // batched logits + log-softmax
    logits_gemm<10><<<dim3(157, 4), dim3(256), 0, stream>>>(Hl + 65536, Wfc_b, bfc, out);
    logsoftmax<<<dim3(640), dim3(256), 0, stream>>>(out);
}

// Round 2
// 2027.524 us; speedup vs baseline: 1.0286x; 1.0286x over previous
//
#include <hip/hip_runtime.h>

typedef unsigned short u16;
typedef __attribute__((ext_vector_type(8))) short bf16x8;
typedef __attribute__((ext_vector_type(4))) float f32x4;

#define DD 2048
#define VV 10000
#define BB 32
#define TT 20

__device__ __forceinline__ u16 f2bf(float f) {
    unsigned u = __float_as_uint(f);
    u += 0x7fffu + ((u >> 16) & 1u);
    return (u16)(u >> 16);
}
__device__ __forceinline__ float bf2f(u16 h) {
    return __uint_as_float(((unsigned)h) << 16);
}

// ---------------------------------------------------------------------------
// One-time: cast the per-step weight matrices to bf16.
// Wcat_a[8192][4096] = [Wih_a[:,0:2048] | Whh_a]      (x = [h_l ; h_a])
// Wcat_l[8192][4096] = [Wih_l[:,0:2048] | Whh_l]      (x = [h_a ; h_l])
// Wfc_b [10016][2048]  (rows 10000..10015 zero-padded for the 32-wide n-tile)
// ---------------------------------------------------------------------------
__global__ __launch_bounds__(256) void cast_weights(
    const float* __restrict__ Wih_a, const float* __restrict__ Whh_a,
    const float* __restrict__ Wih_l, const float* __restrict__ Whh_l,
    const float* __restrict__ Wfc,
    u16* __restrict__ Wcat_a, u16* __restrict__ Wcat_l, u16* __restrict__ Wfc_b)
{
    const long long S1 = 8192LL * 4096;
    const long long S3P = 10016LL * 2048;   // padded Wfc_b
    long long g = (long long)blockIdx.x * 256 + threadIdx.x;
    long long e = g * 4;
    const float* src;
    u16* dst;
    if (e < S1) {
        int n = (int)(e >> 12), k = (int)(e & 4095);
        src = (k < 2048) ? (Wih_a + (size_t)n * 6144 + k)
                         : (Whh_a + (size_t)n * 2048 + (k - 2048));
        dst = Wcat_a + e;
    } else if (e < 2 * S1) {
        long long e2 = e - S1;
        int n = (int)(e2 >> 12), k = (int)(e2 & 4095);
        src = (k < 2048) ? (Wih_l + (size_t)n * 4096 + k)
                         : (Whh_l + (size_t)n * 2048 + (k - 2048));
        dst = Wcat_l + e2;
    } else {
        long long e3 = e - 2 * S1;
        if (e3 >= S3P) return;
        dst = Wfc_b + e3;
        int row = (int)(e3 >> 11);
        if (row >= VV) {                     // zero pad rows 10000..10015
            ushort4 z; z.x = 0; z.y = 0; z.z = 0; z.w = 0;
            *(ushort4*)dst = z;
            return;
        }
        src = Wfc + e3;
    }
    float4 v = *(const float4*)src;
    ushort4 o;
    o.x = f2bf(v.x); o.y = f2bf(v.y); o.z = f2bf(v.z); o.w = f2bf(v.w);
    *(ushort4*)dst = o;
}

// ---------------------------------------------------------------------------
// One-time: v_bar (mean over X), v_hat (sum over X -- attention weights are
// all-ones because softmax is over a singleton axis), zero the LSTM states.
// ---------------------------------------------------------------------------
__global__ __launch_bounds__(256) void prep(
    const float* __restrict__ features,
    u16* __restrict__ vbar, u16* __restrict__ vhat,
    float* __restrict__ c_a, float* __restrict__ c_l,
    u16* __restrict__ Ha0, u16* __restrict__ Hl0)
{
    int i = blockIdx.x * 256 + threadIdx.x;           // 32*2048
    int b = i >> 11, d = i & 2047;
    const float* f = features + (size_t)b * 36 * 2048 + d;
    float s = 0.f;
#pragma unroll
    for (int x = 0; x < 36; ++x) s += f[(size_t)x * 2048];
    vhat[i] = f2bf(s);
    vbar[i] = f2bf(s * (1.f / 36.f));
    c_a[i] = 0.f; c_l[i] = 0.f;
    Ha0[i] = 0;  Hl0[i] = 0;
}

// embedding gather -> bf16, rows m = t*32 + b
__global__ __launch_bounds__(256) void embed_k(
    const float* __restrict__ emb, const int* __restrict__ caption,
    u16* __restrict__ embs)
{
    int i = blockIdx.x * 256 + threadIdx.x;           // 640*2048
    int m = i >> 11, d = i & 2047;
    int t = m >> 5, b = m & 31;
    int tok = caption[b * TT + t];
    embs[i] = f2bf(emb[(size_t)tok * 2048 + d]);
}

// ---------------------------------------------------------------------------
// Small precompute GEMM (M=32): out[m][n] = A[m,:].W[n,kofs:kofs+2048]
//                                           (+bias0[n]+bias1[n])
// Only used for const_a / const_l (one-time, tiny).
// ---------------------------------------------------------------------------
template <int MT>
__global__ __launch_bounds__(256) void pre_gemm(
    const u16* __restrict__ A, const float* __restrict__ W,
    int ldw, int kofs,
    const float* __restrict__ bias0, const float* __restrict__ bias1,
    float* __restrict__ out)
{
    const int lane = threadIdx.x & 63;
    const int wv = threadIdx.x >> 6;
    const int lr = lane & 15, lq = lane >> 4;
    const int n0 = blockIdx.x * 64 + wv * 16;
    const int m0 = blockIdx.y * (MT * 16);

    f32x4 acc[MT];
#pragma unroll
    for (int i = 0; i < MT; ++i) acc[i] = (f32x4){0.f, 0.f, 0.f, 0.f};

    const float* wrow = W + (size_t)(n0 + lr) * ldw + kofs + lq * 8;
    const u16* arow = A + (size_t)(m0 + lr) * 2048 + lq * 8;

    for (int k = 0; k < 2048; k += 32) {
        float4 wlo = *(const float4*)(wrow + k);
        float4 whi = *(const float4*)(wrow + k + 4);
        bf16x8 bf;
        bf[0] = (short)f2bf(wlo.x); bf[1] = (short)f2bf(wlo.y);
        bf[2] = (short)f2bf(wlo.z); bf[3] = (short)f2bf(wlo.w);
        bf[4] = (short)f2bf(whi.x); bf[5] = (short)f2bf(whi.y);
        bf[6] = (short)f2bf(whi.z); bf[7] = (short)f2bf(whi.w);
#pragma unroll
        for (int mt = 0; mt < MT; ++mt) {
            bf16x8 af = *(const bf16x8*)(arow + (size_t)mt * 16 * 2048 + k);
            acc[mt] = __builtin_amdgcn_mfma_f32_16x16x32_bf16(af, bf, acc[mt], 0, 0, 0);
        }
    }
    const int n = n0 + lr;
    float badd = 0.f;
    if (bias0) badd += bias0[n];
    if (bias1) badd += bias1[n];
#pragma unroll
    for (int mt = 0; mt < MT; ++mt) {
#pragma unroll
        for (int r = 0; r < 4; ++r) {
            int m = m0 + mt * 16 + lq * 4 + r;
            out[(size_t)m * 8192 + n] = acc[mt][r] + badd;
        }
    }
}

// ---------------------------------------------------------------------------
// Sequential step kernel v3: A-register-preload + pure W-stream.
// z[32,8192] = x[32,4096] @ Wcat^T,  x = [A0 | A1] (each [32,2048] bf16).
// grid 512 blocks x 512 thr (8 waves).  Block owns 16 W-rows = 4 gates x 4 d
// (d0 = blockIdx.x*4).  Wave w owns K-chunk [w*512, w*512+512):
//   - preloads its A slice (32 rows x 512) into 32 bf16x8 regs (one-time, L2)
//   - inner loop: 16 independent W loads (8-deep static pipeline) + 32 MFMA
// K-partials reduced across the 8 waves in LDS, then fused LSTM gates.
// ---------------------------------------------------------------------------
__global__ __launch_bounds__(512) void step_kernel(
    const u16* __restrict__ A0, const u16* __restrict__ A1,
    const u16* __restrict__ W, const float* __restrict__ zconst,
    float* __restrict__ c, u16* __restrict__ hout)
{
    __shared__ float zred[8][32][17];   // 17.4 KB, padded vs bank conflicts
    const int tid = threadIdx.x;
    const int lane = tid & 63;
    const int w = tid >> 6;                  // 0..7 : K-chunk of 512
    const int lr = lane & 15, lq = lane >> 4;
    const int d0 = blockIdx.x * 4;           // 512 blocks cover 2048 d-cols

    const int g = lr >> 2, dd = lr & 3;      // 16 W-rows: 4 gates x 4 d
    const int nrow = g * 2048 + d0 + dd;

    const u16* Aptr = (w < 4) ? A0 : A1;
    const int kA = (w & 3) * 512 + lq * 8;

    // ---- preload A fragments (32 rows x 512 K) : 32 x bf16x8 = 128 VGPR ----
    const u16* ar0 = Aptr + (size_t)lr * 2048 + kA;
    const u16* ar1 = ar0 + 16 * 2048;
    bf16x8 af0[16], af1[16];
#pragma unroll
    for (int kk = 0; kk < 16; ++kk) {
        af0[kk] = *(const bf16x8*)(ar0 + kk * 32);
        af1[kk] = *(const bf16x8*)(ar1 + kk * 32);
    }

    // ---- stream W: 16 independent loads, 8-deep static pipeline ----
    const u16* wrow = W + (size_t)nrow * 4096 + w * 512 + lq * 8;
    f32x4 acc0 = (f32x4){0.f, 0.f, 0.f, 0.f};
    f32x4 acc1 = (f32x4){0.f, 0.f, 0.f, 0.f};
    bf16x8 wf[8];
#pragma unroll
    for (int kk = 0; kk < 8; ++kk)
        wf[kk] = *(const bf16x8*)(wrow + kk * 32);
#pragma unroll
    for (int kk = 0; kk < 16; ++kk) {
        acc0 = __builtin_amdgcn_mfma_f32_16x16x32_bf16(af0[kk], wf[kk & 7], acc0, 0, 0, 0);
        acc1 = __builtin_amdgcn_mfma_f32_16x16x32_bf16(af1[kk], wf[kk & 7], acc1, 0, 0, 0);
        if (kk < 8)
            wf[kk] = *(const bf16x8*)(wrow + (kk + 8) * 32);
    }

    // ---- K-partials across the 8 waves via LDS ----
#pragma unroll
    for (int r = 0; r < 4; ++r) {
        zred[w][lq * 4 + r][lr]      = acc0[r];
        zred[w][16 + lq * 4 + r][lr] = acc1[r];
    }
    __syncthreads();

    // ---- gates: 128 threads <-> (b, j) with j in 0..3 (d = d0+j) ----
    if (tid < 128) {
        const int b = tid >> 2;
        const int j = tid & 3;
        const int d = d0 + j;
        float z[4];
#pragma unroll
        for (int gg = 0; gg < 4; ++gg) {
            float s = zconst[(size_t)b * 8192 + gg * 2048 + d];
#pragma unroll
            for (int wv = 0; wv < 8; ++wv) s += zred[wv][b][gg * 4 + j];
            z[gg] = s;
        }
        float ig = 1.f / (1.f + __expf(-z[0]));
        float fg = 1.f / (1.f + __expf(-z[1]));
        float gv = tanhf(z[2]);
        float og = 1.f / (1.f + __expf(-z[3]));
        float cn = fg * c[(size_t)b * 2048 + d] + ig * gv;
        c[(size_t)b * 2048 + d] = cn;
        hout[(size_t)b * 2048 + d] = f2bf(og * tanhf(cn));
    }
}

// ---------------------------------------------------------------------------
// Big batched GEMM over M=640 rows, per-wave 64m x 32n tile, K=2048.
// MODE 0: z_const = embs @ Wih_a[:,4096:6144]^T + addend[b][n]
//         (W read as fp32 with inline bf16 cast; N = 8192; out[m][8192])
// MODE 1: logits  = Hl @ Wfc_b^T + bias  (W bf16 [10016,2048];
//         out scatter [b][t][10000], guard n < 10000)
// m-fastest wave mapping + bijective XCD swizzle: the 10 waves sharing one
// W-panel land on one XCD's L2 -> W fetched ~once from HBM.
// ---------------------------------------------------------------------------
template <int MODE>
__global__ __launch_bounds__(256) void big_gemm(
    const u16* __restrict__ A, const void* __restrict__ Wp,
    const float* __restrict__ extra, float* __restrict__ out)
{
    const int NWN = MODE ? 313 : 256;        // n-tiles of 32
    const int nwg = MODE ? 783 : 640;
    int bid = blockIdx.x;
    {   // bijective XCD swizzle (m204 form)
        int q = nwg >> 3, r = nwg & 7, x = bid & 7, o = bid >> 3;
        bid = (x < r ? x * (q + 1) : r * (q + 1) + (x - r) * q) + o;
    }
    const int gw = bid * 4 + (int)(threadIdx.x >> 6);
    const int wm = gw % 10;                  // m-fastest: W-panel reuse
    const int wn = gw / 10;
    if (wn >= NWN) return;
    const int lane = threadIdx.x & 63;
    const int lr = lane & 15, lq = lane >> 4;
    const int m0 = wm * 64, n0 = wn * 32;

    f32x4 acc[4][2];
#pragma unroll
    for (int mt = 0; mt < 4; ++mt)
#pragma unroll
        for (int nt = 0; nt < 2; ++nt) acc[mt][nt] = (f32x4){0.f, 0.f, 0.f, 0.f};

    const u16* arow = A + (size_t)(m0 + lr) * 2048 + lq * 8;

    if (MODE == 1) {
        const u16* Wb = (const u16*)Wp;
        const u16* wrow0 = Wb + (size_t)(n0 + lr) * 2048 + lq * 8;
        const u16* wrow1 = wrow0 + 16 * 2048;
#pragma unroll 2
        for (int k = 0; k < 2048; k += 32) {
            bf16x8 w0 = *(const bf16x8*)(wrow0 + k);
            bf16x8 w1 = *(const bf16x8*)(wrow1 + k);
#pragma unroll
            for (int mt = 0; mt < 4; ++mt) {
                bf16x8 a = *(const bf16x8*)(arow + (size_t)mt * 16 * 2048 + k);
                acc[mt][0] = __builtin_amdgcn_mfma_f32_16x16x32_bf16(a, w0, acc[mt][0], 0, 0, 0);
                acc[mt][1] = __builtin_amdgcn_mfma_f32_16x16x32_bf16(a, w1, acc[mt][1], 0, 0, 0);
            }
        }
    } else {
        const float* Wf = (const float*)Wp;
        const float* wrow0 = Wf + (size_t)(n0 + lr) * 6144 + 4096 + lq * 8;
        const float* wrow1 = wrow0 + (size_t)16 * 6144;
#pragma unroll 2
        for (int k = 0; k < 2048; k += 32) {
            float4 p0 = *(const float4*)(wrow0 + k);
            float4 p1 = *(const float4*)(wrow0 + k + 4);
            float4 q0 = *(const float4*)(wrow1 + k);
            float4 q1 = *(const float4*)(wrow1 + k + 4);
            bf16x8 w0, w1;
            w0[0] = (short)f2bf(p0.x); w0[1] = (short)f2bf(p0.y);
            w0[2] = (short)f2bf(p0.z); w0[3] = (short)f2bf(p0.w);
            w0[4] = (short)f2bf(p1.x); w0[5] = (short)f2bf(p1.y);
            w0[6] = (short)f2bf(p1.z); w0[7] = (short)f2bf(p1.w);
            w1[0] = (short)f2bf(q0.x); w1[1] = (short)f2bf(q0.y);
            w1[2] = (short)f2bf(q0.z); w1[3] = (short)f2bf(q0.w);
            w1[4] = (short)f2bf(q1.x); w1[5] = (short)f2bf(q1.y);
            w1[6] = (short)f2bf(q1.z); w1[7] = (short)f2bf(q1.w);
#pragma unroll
            for (int mt = 0; mt < 4; ++mt) {
                bf16x8 a = *(const bf16x8*)(arow + (size_t)mt * 16 * 2048 + k);
                acc[mt][0] = __builtin_amdgcn_mfma_f32_16x16x32_bf16(a, w0, acc[mt][0], 0, 0, 0);
                acc[mt][1] = __builtin_amdgcn_mfma_f32_16x16x32_bf16(a, w1, acc[mt][1], 0, 0, 0);
            }
        }
    }

#pragma unroll
    for (int mt = 0; mt < 4; ++mt) {
#pragma unroll
        for (int nt = 0; nt < 2; ++nt) {
            const int n = n0 + nt * 16 + lr;
#pragma unroll
            for (int r = 0; r < 4; ++r) {
                const int m = m0 + mt * 16 + lq * 4 + r;
                if (MODE == 0) {
                    out[(size_t)m * 8192 + n] =
                        acc[mt][nt][r] + extra[(size_t)(m & 31) * 8192 + n];
                } else {
                    if (n < VV) {
                        const int t = m >> 5, b = m & 31;
                        out[(size_t)b * (TT * VV) + (size_t)t * VV + n] =
                            acc[mt][nt][r] + extra[n];
                    }
                }
            }
        }
    }
}

// in-place log-softmax over rows of 10000
__global__ __launch_bounds__(256) void logsoftmax(float* __restrict__ out)
{
    float* p = out + (size_t)blockIdx.x * VV;
    const int tid = threadIdx.x, lane = tid & 63, wv = tid >> 6;
    __shared__ float red[4], red2[4];
    float mx = -1e30f;
    for (int i = tid; i < VV; i += 256) mx = fmaxf(mx, p[i]);
    for (int o = 32; o > 0; o >>= 1) mx = fmaxf(mx, __shfl_down(mx, o, 64));
    if (lane == 0) red[wv] = mx;
    __syncthreads();
    mx = fmaxf(fmaxf(red[0], red[1]), fmaxf(red[2], red[3]));
    float sum = 0.f;
    for (int i = tid; i < VV; i += 256) sum += __expf(p[i] - mx);
    for (int o = 32; o > 0; o >>= 1) sum += __shfl_down(sum, o, 64);
    if (lane == 0) red2[wv] = sum;
    __syncthreads();
    sum = red2[0] + red2[1] + red2[2] + red2[3];
    const float lse = mx + __logf(sum);
    for (int i = tid; i < VV; i += 256) p[i] = p[i] - lse;
}

// ---------------------------------------------------------------------------
extern "C" void kernel_launch(void* const* d_in, const int* in_sizes, int n_in,
                              void* d_out, int out_size, void* d_ws, size_t ws_size,
                              hipStream_t stream)
{
    const float* features = (const float*)d_in[0];
    const int*   caption  = (const int*)d_in[1];
    const float* emb      = (const float*)d_in[2];
    const float* Wih_a    = (const float*)d_in[3];
    const float* Whh_a    = (const float*)d_in[4];
    const float* bih_a    = (const float*)d_in[5];
    const float* bhh_a    = (const float*)d_in[6];
    const float* Wih_l    = (const float*)d_in[7];
    const float* Whh_l    = (const float*)d_in[8];
    const float* bih_l    = (const float*)d_in[9];
    const float* bhh_l    = (const float*)d_in[10];
    // d_in[11..16] = Wv,bv,Wh,bh,Wa,ba : DEAD (softmax over singleton axis)
    const float* Wfc      = (const float*)d_in[17];
    const float* bfc      = (const float*)d_in[18];
    float* out = (float*)d_out;

    char* ws = (char*)d_ws;
    size_t off = 0;
    auto alloc = [&](size_t bytes) { void* p = ws + off; off += (bytes + 255) & ~(size_t)255; return p; };
    u16* Wcat_a  = (u16*)alloc(8192ull * 4096 * 2);       // 67.1 MB
    u16* Wcat_l  = (u16*)alloc(8192ull * 4096 * 2);       // 67.1 MB
    u16* Wfc_b   = (u16*)alloc(10016ull * 2048 * 2);      // 41.0 MB (padded)
    float* z_const = (float*)alloc(20ull * 32 * 8192 * 4);// 21.0 MB
    float* const_a = (float*)alloc(32ull * 8192 * 4);
    float* const_l = (float*)alloc(32ull * 8192 * 4);
    u16* embs    = (u16*)alloc(640ull * 2048 * 2);
    u16* vbar    = (u16*)alloc(32ull * 2048 * 2);
    u16* vhat    = (u16*)alloc(32ull * 2048 * 2);
    u16* Ha      = (u16*)alloc(2ull * 32 * 2048 * 2);
    u16* Hl      = (u16*)alloc(21ull * 32 * 2048 * 2);
    float* c_a   = (float*)alloc(32ull * 2048 * 4);
    float* c_l   = (float*)alloc(32ull * 2048 * 4);
    (void)ws_size; (void)in_sizes; (void)n_in; (void)out_size;

    // one-time precompute
    cast_weights<<<dim3(85568), dim3(256), 0, stream>>>(
        Wih_a, Whh_a, Wih_l, Whh_l, Wfc, Wcat_a, Wcat_l, Wfc_b);
    prep<<<dim3(256), dim3(256), 0, stream>>>(features, vbar, vhat, c_a, c_l, Ha, Hl);
    embed_k<<<dim3(5120), dim3(256), 0, stream>>>(emb, caption, embs);
    // const_a[b][n] = vbar @ Wih_a[:,2048:4096]^T + bih_a + bhh_a
    pre_gemm<2><<<dim3(128, 1), dim3(256), 0, stream>>>(
        vbar, Wih_a, 6144, 2048, bih_a, bhh_a, const_a);
    // const_l[b][n] = vhat @ Wih_l[:,2048:4096]^T + bih_l + bhh_l
    pre_gemm<2><<<dim3(128, 1), dim3(256), 0, stream>>>(
        vhat, Wih_l, 4096, 2048, bih_l, bhh_l, const_l);
    // z_const[t*32+b][n] = embs @ Wih_a[:,4096:6144]^T + const_a[b]
    big_gemm<0><<<dim3(640), dim3(256), 0, stream>>>(
        embs, (const void*)Wih_a, const_a, z_const);

    // sequential 20-step dual-LSTM loop (2 fused GEMM+gate kernels per step)
    for (int t = 0; t < 20; ++t) {
        u16* hl_prev = Hl + (size_t)t * 65536;
        u16* ha_prev = Ha + (size_t)(t & 1) * 65536;
        u16* ha_new  = Ha + (size_t)((t + 1) & 1) * 65536;
        u16* hl_new  = Hl + (size_t)(t + 1) * 65536;
        // attention LSTM: x=[h_l ; h_a] vs [Wih_a[:,0:2048] | Whh_a]
        step_kernel<<<dim3(512), dim3(512), 0, stream>>>(
            hl_prev, ha_prev, Wcat_a, z_const + (size_t)t * 262144, c_a, ha_new);
        // language LSTM: x=[h_a ; h_l] vs [Wih_l[:,0:2048] | Whh_l]
        step_kernel<<<dim3(512), dim3(512), 0, stream>>>(
            ha_new, hl_prev, Wcat_l, const_l, c_l, hl_new);
    }

    // batched logits + log-softmax
    big_gemm<1><<<dim3(783), dim3(256), 0, stream>>>(
        Hl + 65536, (const void*)Wfc_b, bfc, out);
    logsoftmax<<<dim3(640), dim3(256), 0, stream>>>(out);
}

// Round 3
// 1735.688 us; speedup vs baseline: 1.2015x; 1.1681x over previous
//
#include <hip/hip_runtime.h>

typedef unsigned short u16;
typedef __attribute__((ext_vector_type(8))) short bf16x8;
typedef __attribute__((ext_vector_type(4))) float f32x4;

#define DD 2048
#define VV 10000
#define BB 32
#define TT 20

__device__ __forceinline__ u16 f2bf(float f) {
    unsigned u = __float_as_uint(f);
    u += 0x7fffu + ((u >> 16) & 1u);
    return (u16)(u >> 16);
}

// ===========================================================================
// Packed W layouts (pre-swizzled so kernel loads are wave-contiguous 1KB):
//
// STEP layout (Wcat_a / Wcat_l, logical [8192][4096] = [Wih[:,0:2048]|Whh]):
//   phys = (((blk*8 + w)*16 + kk)*2 + nt)*512 + lane*8 + j
//   logical n = (lr>>2)*2048 + blk*8 + nt*4 + (lr&3)   [gate, d-col]
//           k = w*512 + kk*32 + lq*8 + j
//   (blk<256, w<8, kk<16, nt<2, lane=lq*16+lr<64, j<8)
//
// GEMM layout (Wfc_p / Wza_p / Wcl_p, n-tiles of 32 = 2x16):
//   phys = ((wn*KS + ks)*2 + nt)*512 + lane*8 + j
//   logical n = wn*32 + nt*16 + lr ;  k = ks*32 + lq*8 + j   (KS = K/32)
// ===========================================================================
__global__ __launch_bounds__(256) void pack_weights(
    const float* __restrict__ Wih_a, const float* __restrict__ Whh_a,
    const float* __restrict__ Wih_l, const float* __restrict__ Whh_l,
    const float* __restrict__ Wfc,
    u16* __restrict__ Wcat_a, u16* __restrict__ Wcat_l,
    u16* __restrict__ Wfc_p, u16* __restrict__ Wza_p, u16* __restrict__ Wcl_p)
{
    const size_t E0 = 33554432ull;               // Wcat_a elements
    const size_t E1 = 67108864ull;               // + Wcat_l
    const size_t E2 = 87621632ull;               // + Wfc_p (10016*2048)
    const size_t E3 = 121176064ull;              // + Wza_p (8192*4096)
    const size_t E4 = 137953280ull;              // + Wcl_p (8192*2048)
    size_t ph = ((size_t)blockIdx.x * 256 + threadIdx.x) * 8;
    if (ph >= E4) return;
    const float* src;
    u16* dst;
    if (ph < E1) {                               // step layouts
        size_t p = ph;
        const float* Wih = Wih_a; const float* Whh = Whh_a;
        size_t ldw = 6144;
        u16* base = Wcat_a;
        if (p >= E0) { p -= E0; Wih = Wih_l; Whh = Whh_l; ldw = 4096; base = Wcat_l; }
        int lane = (int)((p >> 3) & 63), lr = lane & 15, lq = lane >> 4;
        int nt = (int)((p >> 9) & 1);
        int kk = (int)((p >> 10) & 15);
        int w  = (int)((p >> 14) & 7);
        int blk = (int)(p >> 17);
        int n = (lr >> 2) * 2048 + blk * 8 + nt * 4 + (lr & 3);
        int k = w * 512 + kk * 32 + lq * 8;
        src = (k < 2048) ? (Wih + (size_t)n * ldw + k)
                         : (Whh + (size_t)n * 2048 + (k - 2048));
        dst = base + p;
    } else if (ph < E2) {                        // Wfc_p : KS=64, N=10016 pad
        size_t p = ph - E1;
        int lane = (int)((p >> 3) & 63), lr = lane & 15, lq = lane >> 4;
        int nt = (int)((p >> 9) & 1);
        int ks = (int)((p >> 10) & 63);
        int wn = (int)(p >> 16);
        int n = wn * 32 + nt * 16 + lr;
        int k = ks * 32 + lq * 8;
        dst = Wfc_p + p;
        if (n >= VV) {
            ushort4 z; z.x = 0; z.y = 0; z.z = 0; z.w = 0;
            *(ushort4*)dst = z; *(ushort4*)(dst + 4) = z;
            return;
        }
        src = Wfc + (size_t)n * 2048 + k;
    } else if (ph < E3) {                        // Wza_p : KS=128, Wih_a[:,2048:6144]
        size_t p = ph - E2;
        int lane = (int)((p >> 3) & 63), lr = lane & 15, lq = lane >> 4;
        int nt = (int)((p >> 9) & 1);
        int ks = (int)((p >> 10) & 127);
        int wn = (int)(p >> 17);
        int n = wn * 32 + nt * 16 + lr;
        int k = ks * 32 + lq * 8;
        src = Wih_a + (size_t)n * 6144 + 2048 + k;
        dst = Wza_p + p;
    } else {                                     // Wcl_p : KS=64, Wih_l[:,2048:4096]
        size_t p = ph - E3;
        int lane = (int)((p >> 3) & 63), lr = lane & 15, lq = lane >> 4;
        int nt = (int)((p >> 9) & 1);
        int ks = (int)((p >> 10) & 63);
        int wn = (int)(p >> 16);
        int n = wn * 32 + nt * 16 + lr;
        int k = ks * 32 + lq * 8;
        src = Wih_l + (size_t)n * 4096 + 2048 + k;
        dst = Wcl_p + p;
    }
    float4 lo = *(const float4*)src;
    float4 hi = *(const float4*)(src + 4);
    ushort4 o0, o1;
    o0.x = f2bf(lo.x); o0.y = f2bf(lo.y); o0.z = f2bf(lo.z); o0.w = f2bf(lo.w);
    o1.x = f2bf(hi.x); o1.y = f2bf(hi.y); o1.z = f2bf(hi.z); o1.w = f2bf(hi.w);
    *(ushort4*)dst = o0;
    *(ushort4*)(dst + 4) = o1;
}

// ---------------------------------------------------------------------------
// One-time: v_bar (mean over X), v_hat (sum over X -- attention weights are
// all-ones because softmax is over a singleton axis), zero the LSTM states.
// ---------------------------------------------------------------------------
__global__ __launch_bounds__(256) void prep(
    const float* __restrict__ features,
    u16* __restrict__ vbar, u16* __restrict__ vhat,
    float* __restrict__ c_a, float* __restrict__ c_l,
    u16* __restrict__ Ha0, u16* __restrict__ Hl0)
{
    int i = blockIdx.x * 256 + threadIdx.x;           // 32*2048
    int b = i >> 11, d = i & 2047;
    const float* f = features + (size_t)b * 36 * 2048 + d;
    float s = 0.f;
#pragma unroll
    for (int x = 0; x < 36; ++x) s += f[(size_t)x * 2048];
    vhat[i] = f2bf(s);
    vbar[i] = f2bf(s * (1.f / 36.f));
    c_a[i] = 0.f; c_l[i] = 0.f;
    Ha0[i] = 0;  Hl0[i] = 0;
}

// A_aug[m][4096] = [vbar_b | emb_token(t,b)]  (rows m = t*32+b), bf16
__global__ __launch_bounds__(256) void embed_aug(
    const float* __restrict__ emb, const int* __restrict__ caption,
    const u16* __restrict__ vbar, u16* __restrict__ A_aug)
{
    int idx = blockIdx.x * 256 + threadIdx.x;         // 640*512 (8 elems each)
    int m = idx >> 9;
    int col8 = (idx & 511) * 8;
    int t = m >> 5, b = m & 31;
    u16* dst = A_aug + (size_t)m * 4096 + col8;
    if (col8 < 2048) {
        ushort4 v0 = *(const ushort4*)(vbar + (size_t)b * 2048 + col8);
        ushort4 v1 = *(const ushort4*)(vbar + (size_t)b * 2048 + col8 + 4);
        *(ushort4*)dst = v0; *(ushort4*)(dst + 4) = v1;
    } else {
        int tok = caption[b * TT + t];
        const float* s = emb + (size_t)tok * 2048 + (col8 - 2048);
        float4 lo = *(const float4*)s, hi = *(const float4*)(s + 4);
        ushort4 o0, o1;
        o0.x = f2bf(lo.x); o0.y = f2bf(lo.y); o0.z = f2bf(lo.z); o0.w = f2bf(lo.w);
        o1.x = f2bf(hi.x); o1.y = f2bf(hi.y); o1.z = f2bf(hi.z); o1.w = f2bf(hi.w);
        *(ushort4*)dst = o0; *(ushort4*)(dst + 4) = o1;
    }
}

// ---------------------------------------------------------------------------
// Packed-W batched GEMM.  Per-wave tile: MT*16 m-rows x 32 n-cols, K = KS*32.
// W stream per wave: contiguous 2KB per k-step (packed GEMM layout).
// MODE 0: out[m][8192] = acc + b0[n] + b1[n]        (z_const / const_l)
// MODE 1: out[b][t][VV] = acc + b0[n], guard n<VV   (logits)
// wm-fastest wave order + bijective XCD swizzle -> waves sharing a W panel
// land on one XCD's L2.
// ---------------------------------------------------------------------------
template <int KS, int NWN, int NM, int MT, int MODE>
__global__ __launch_bounds__(256) void gemm_p(
    const u16* __restrict__ A, const u16* __restrict__ Wp,
    const float* __restrict__ b0, const float* __restrict__ b1,
    float* __restrict__ out)
{
    const int K = KS * 32;
    const int nwaves = NM * NWN;
    const int nwg = (nwaves + 3) >> 2;
    int bid = blockIdx.x;
    {   // bijective XCD swizzle
        int q = nwg >> 3, r = nwg & 7, x = bid & 7, o = bid >> 3;
        bid = (x < r ? x * (q + 1) : r * (q + 1) + (x - r) * q) + o;
    }
    const int gw = bid * 4 + (int)(threadIdx.x >> 6);
    if (gw >= nwaves) return;
    const int wm = gw % NM, wn = gw / NM;
    const int lane = threadIdx.x & 63;
    const int lr = lane & 15, lq = lane >> 4;
    const int m0 = wm * (MT * 16);

    f32x4 acc[MT][2];
#pragma unroll
    for (int mt = 0; mt < MT; ++mt) {
        acc[mt][0] = (f32x4){0.f, 0.f, 0.f, 0.f};
        acc[mt][1] = (f32x4){0.f, 0.f, 0.f, 0.f};
    }
    const u16* arow = A + (size_t)(m0 + lr) * K + lq * 8;
    const u16* wptr = Wp + (size_t)wn * (KS * 1024) + lane * 8;

#pragma unroll 4
    for (int ks = 0; ks < KS; ++ks) {
        bf16x8 w0 = *(const bf16x8*)(wptr + (size_t)ks * 1024);
        bf16x8 w1 = *(const bf16x8*)(wptr + (size_t)ks * 1024 + 512);
#pragma unroll
        for (int mt = 0; mt < MT; ++mt) {
            bf16x8 a = *(const bf16x8*)(arow + (size_t)mt * 16 * K + ks * 32);
            acc[mt][0] = __builtin_amdgcn_mfma_f32_16x16x32_bf16(a, w0, acc[mt][0], 0, 0, 0);
            acc[mt][1] = __builtin_amdgcn_mfma_f32_16x16x32_bf16(a, w1, acc[mt][1], 0, 0, 0);
        }
    }

#pragma unroll
    for (int nt = 0; nt < 2; ++nt) {
        const int n = wn * 32 + nt * 16 + lr;
        float badd = 0.f;
        if (b0) badd += b0[n < (MODE ? VV : 8192) ? n : 0];
        if (b1) badd += b1[n < 8192 ? n : 0];
#pragma unroll
        for (int mt = 0; mt < MT; ++mt) {
#pragma unroll
            for (int r = 0; r < 4; ++r) {
                const int m = m0 + mt * 16 + lq * 4 + r;
                float v = acc[mt][nt][r] + badd;
                if (MODE == 0) {
                    out[(size_t)m * 8192 + n] = v;
                } else {
                    if (n < VV) {
                        const int t = m >> 5, b = m & 31;
                        out[(size_t)b * (TT * VV) + (size_t)t * VV + n] = v;
                    }
                }
            }
        }
    }
}

// ---------------------------------------------------------------------------
// Sequential step kernel v4: packed contiguous W stream.
// z[32,8192] = x[32,4096] @ Wcat^T,  x = [A0 | A1] (each [32,2048] bf16).
// 256 blocks x 512 thr (8 waves), 1 block/CU.  Block owns 32 W-rows
// (4 gates x 8 d, d0 = blk*8).  Wave w owns K-chunk [w*512, (w+1)*512):
//   A slice (32 rows x 512) preloaded into 128 VGPRs (L2-resident),
//   W read as ONE sequential 32KB stream (1KB wave-contiguous per load,
//   8-deep pipeline -> 128KB in flight per CU).
// K-partials reduced across waves in LDS, then fused LSTM gates.
// ---------------------------------------------------------------------------
__global__ __launch_bounds__(512, 2) void step_kernel(
    const u16* __restrict__ A0, const u16* __restrict__ A1,
    const u16* __restrict__ Wp, const float* __restrict__ zconst,
    float* __restrict__ c, u16* __restrict__ hout)
{
    __shared__ float zred[8][32][33];   // 33.8 KB, padded
    const int tid = threadIdx.x;
    const int lane = tid & 63;
    const int w = tid >> 6;                  // 0..7 : K-chunk of 512
    const int lr = lane & 15, lq = lane >> 4;
    const int blk = blockIdx.x;              // d0 = blk*8

    const u16* Aptr = (w < 4) ? A0 : A1;
    const int kA = (w & 3) * 512 + lq * 8;

    // ---- preload A fragments (rows 0..31 x 512 K) : 32 x bf16x8 = 128 VGPR
    const u16* ar0 = Aptr + (size_t)lr * 2048 + kA;
    const u16* ar1 = ar0 + 16 * 2048;
    bf16x8 af0[16], af1[16];
#pragma unroll
    for (int kk = 0; kk < 16; ++kk) {
        af0[kk] = *(const bf16x8*)(ar0 + kk * 32);
        af1[kk] = *(const bf16x8*)(ar1 + kk * 32);
    }

    // ---- W: one contiguous 32KB stream per wave, 8-deep pipeline ----
    const u16* wbase = Wp + ((size_t)blk * 8 + w) * 16384 + lane * 8;
    f32x4 acc[2][2];
    acc[0][0] = (f32x4){0.f, 0.f, 0.f, 0.f};
    acc[0][1] = (f32x4){0.f, 0.f, 0.f, 0.f};
    acc[1][0] = (f32x4){0.f, 0.f, 0.f, 0.f};
    acc[1][1] = (f32x4){0.f, 0.f, 0.f, 0.f};
    bf16x8 wf[8][2];
#pragma unroll
    for (int kk = 0; kk < 8; ++kk) {
        wf[kk][0] = *(const bf16x8*)(wbase + kk * 1024);
        wf[kk][1] = *(const bf16x8*)(wbase + kk * 1024 + 512);
    }
#pragma unroll
    for (int kk = 0; kk < 16; ++kk) {
        bf16x8 w0 = wf[kk & 7][0];
        bf16x8 w1 = wf[kk & 7][1];
        if (kk < 8) {
            wf[kk][0] = *(const bf16x8*)(wbase + (kk + 8) * 1024);
            wf[kk][1] = *(const bf16x8*)(wbase + (kk + 8) * 1024 + 512);
        }
        acc[0][0] = __builtin_amdgcn_mfma_f32_16x16x32_bf16(af0[kk], w0, acc[0][0], 0, 0, 0);
        acc[1][0] = __builtin_amdgcn_mfma_f32_16x16x32_bf16(af1[kk], w0, acc[1][0], 0, 0, 0);
        acc[0][1] = __builtin_amdgcn_mfma_f32_16x16x32_bf16(af0[kk], w1, acc[0][1], 0, 0, 0);
        acc[1][1] = __builtin_amdgcn_mfma_f32_16x16x32_bf16(af1[kk], w1, acc[1][1], 0, 0, 0);
    }

    // ---- K-partials across the 8 waves via LDS ----
#pragma unroll
    for (int nt = 0; nt < 2; ++nt)
#pragma unroll
        for (int r = 0; r < 4; ++r) {
            zred[w][lq * 4 + r][nt * 16 + lr]      = acc[0][nt][r];
            zred[w][16 + lq * 4 + r][nt * 16 + lr] = acc[1][nt][r];
        }
    __syncthreads();

    // ---- gates: 256 threads <-> (b, j) with j in 0..7 (d = blk*8+j) ----
    if (tid < 256) {
        const int b = tid >> 3;
        const int j = tid & 7;
        const int d = blk * 8 + j;
        float z[4];
#pragma unroll
        for (int gg = 0; gg < 4; ++gg) {
            const int col = (j >> 2) * 16 + gg * 4 + (j & 3);
            float s = zconst[(size_t)b * 8192 + gg * 2048 + d];
#pragma unroll
            for (int wv = 0; wv < 8; ++wv) s += zred[wv][b][col];
            z[gg] = s;
        }
        float ig = 1.f / (1.f + __expf(-z[0]));
        float fg = 1.f / (1.f + __expf(-z[1]));
        float gv = tanhf(z[2]);
        float og = 1.f / (1.f + __expf(-z[3]));
        float cn = fg * c[(size_t)b * 2048 + d] + ig * gv;
        c[(size_t)b * 2048 + d] = cn;
        hout[(size_t)b * 2048 + d] = f2bf(og * tanhf(cn));
    }
}

// in-place log-softmax over rows of 10000
__global__ __launch_bounds__(256) void logsoftmax(float* __restrict__ out)
{
    float* p = out + (size_t)blockIdx.x * VV;
    const int tid = threadIdx.x, lane = tid & 63, wv = tid >> 6;
    __shared__ float red[4], red2[4];
    float mx = -1e30f;
    for (int i = tid; i < VV; i += 256) mx = fmaxf(mx, p[i]);
    for (int o = 32; o > 0; o >>= 1) mx = fmaxf(mx, __shfl_down(mx, o, 64));
    if (lane == 0) red[wv] = mx;
    __syncthreads();
    mx = fmaxf(fmaxf(red[0], red[1]), fmaxf(red[2], red[3]));
    float sum = 0.f;
    for (int i = tid; i < VV; i += 256) sum += __expf(p[i] - mx);
    for (int o = 32; o > 0; o >>= 1) sum += __shfl_down(sum, o, 64);
    if (lane == 0) red2[wv] = sum;
    __syncthreads();
    sum = red2[0] + red2[1] + red2[2] + red2[3];
    const float lse = mx + __logf(sum);
    for (int i = tid; i < VV; i += 256) p[i] = p[i] - lse;
}

// ---------------------------------------------------------------------------
extern "C" void kernel_launch(void* const* d_in, const int* in_sizes, int n_in,
                              void* d_out, int out_size, void* d_ws, size_t ws_size,
                              hipStream_t stream)
{
    const float* features = (const float*)d_in[0];
    const int*   caption  = (const int*)d_in[1];
    const float* emb      = (const float*)d_in[2];
    const float* Wih_a    = (const float*)d_in[3];
    const float* Whh_a    = (const float*)d_in[4];
    const float* bih_a    = (const float*)d_in[5];
    const float* bhh_a    = (const float*)d_in[6];
    const float* Wih_l    = (const float*)d_in[7];
    const float* Whh_l    = (const float*)d_in[8];
    const float* bih_l    = (const float*)d_in[9];
    const float* bhh_l    = (const float*)d_in[10];
    // d_in[11..16] = Wv,bv,Wh,bh,Wa,ba : DEAD (softmax over singleton axis)
    const float* Wfc      = (const float*)d_in[17];
    const float* bfc      = (const float*)d_in[18];
    float* out = (float*)d_out;

    char* ws = (char*)d_ws;
    size_t off = 0;
    auto alloc = [&](size_t bytes) { void* p = ws + off; off += (bytes + 255) & ~(size_t)255; return p; };
    u16* Wcat_a  = (u16*)alloc(33554432ull * 2);          // 67.1 MB
    u16* Wcat_l  = (u16*)alloc(33554432ull * 2);          // 67.1 MB
    u16* Wfc_p   = (u16*)alloc(20512768ull * 2);          // 41.0 MB
    u16* Wza_p   = (u16*)alloc(33554432ull * 2);          // 67.1 MB
    u16* Wcl_p   = (u16*)alloc(16777216ull * 2);          // 33.6 MB
    float* z_const = (float*)alloc(20ull * 32 * 8192 * 4);// 21.0 MB
    float* const_l = (float*)alloc(32ull * 8192 * 4);
    u16* A_aug   = (u16*)alloc(640ull * 4096 * 2);        // 5.2 MB
    u16* vbar    = (u16*)alloc(32ull * 2048 * 2);
    u16* vhat    = (u16*)alloc(32ull * 2048 * 2);
    u16* Ha      = (u16*)alloc(2ull * 32 * 2048 * 2);
    u16* Hl      = (u16*)alloc(21ull * 32 * 2048 * 2);
    float* c_a   = (float*)alloc(32ull * 2048 * 4);
    float* c_l   = (float*)alloc(32ull * 2048 * 4);
    (void)ws_size; (void)in_sizes; (void)n_in; (void)out_size;

    // one-time precompute
    pack_weights<<<dim3(67360), dim3(256), 0, stream>>>(
        Wih_a, Whh_a, Wih_l, Whh_l, Wfc, Wcat_a, Wcat_l, Wfc_p, Wza_p, Wcl_p);
    prep<<<dim3(256), dim3(256), 0, stream>>>(features, vbar, vhat, c_a, c_l, Ha, Hl);
    embed_aug<<<dim3(1280), dim3(256), 0, stream>>>(emb, caption, vbar, A_aug);
    // const_l[b][n] = vhat @ Wih_l[:,2048:4096]^T + bih_l + bhh_l
    gemm_p<64, 256, 1, 2, 0><<<dim3(64), dim3(256), 0, stream>>>(
        vhat, Wcl_p, bih_l, bhh_l, const_l);
    // z_const[t*32+b][n] = [vbar|emb] @ Wih_a[:,2048:6144]^T + bih_a + bhh_a
    gemm_p<128, 256, 10, 4, 0><<<dim3(640), dim3(256), 0, stream>>>(
        A_aug, Wza_p, bih_a, bhh_a, z_const);

    // sequential 20-step dual-LSTM loop (2 fused GEMM+gate kernels per step)
    for (int t = 0; t < 20; ++t) {
        u16* hl_prev = Hl + (size_t)t * 65536;
        u16* ha_prev = Ha + (size_t)(t & 1) * 65536;
        u16* ha_new  = Ha + (size_t)((t + 1) & 1) * 65536;
        u16* hl_new  = Hl + (size_t)(t + 1) * 65536;
        // attention LSTM: x=[h_l ; h_a] vs [Wih_a[:,0:2048] | Whh_a]
        step_kernel<<<dim3(256), dim3(512), 0, stream>>>(
            hl_prev, ha_prev, Wcat_a, z_const + (size_t)t * 262144, c_a, ha_new);
        // language LSTM: x=[h_a ; h_l] vs [Wih_l[:,0:2048] | Whh_l]
        step_kernel<<<dim3(256), dim3(512), 0, stream>>>(
            ha_new, hl_prev, Wcat_l, const_l, c_l, hl_new);
    }

    // batched logits + log-softmax
    gemm_p<64, 313, 10, 4, 1><<<dim3(783), dim3(256), 0, stream>>>(
        Hl + 65536, Wfc_p, bfc, nullptr, out);
    logsoftmax<<<dim3(640), dim3(256), 0, stream>>>(out);
}